// Round 4
// baseline (596.586 us; speedup 1.0000x reference)
//
#include <hip/hip_runtime.h>
#include <stdint.h>

// Problem constants
#define B_  4
#define S_  2048
#define D_  1024
#define H_  16
#define DK_ 64
#define M_  8192   // B_*S_

typedef __attribute__((ext_vector_type(8))) short bf16x8;
typedef __attribute__((ext_vector_type(4))) float f32x4;

static __device__ __forceinline__ short f2bf(float f) {
  union { float f; uint32_t u; } c; c.f = f;
  uint32_t u = c.u;
  uint32_t r = (u + 0x7FFFu + ((u >> 16) & 1u)) >> 16;  // RNE
  return (short)r;
}
static __device__ __forceinline__ float bf2f(short h) {
  union { uint32_t u; float f; } c; c.u = ((uint32_t)(uint16_t)h) << 16;
  return c.f;
}
static __device__ __forceinline__ void split1(float v, short& hi, short& lo) {
  hi = f2bf(v);
  lo = f2bf(v - bf2f(hi));
}

// ---------------------------------------------------------------------------
// Weight convert+transpose+split: Wt_hi[n][k], Wt_lo[n][k] bf16 per weight.
// ---------------------------------------------------------------------------
__global__ __launch_bounds__(256) void kw_split(
    const float* __restrict__ w0, const float* __restrict__ w1,
    const float* __restrict__ w2, const float* __restrict__ w3,
    short* __restrict__ wt)
{
  __shared__ float tile[32][33];
  const float* src;
  switch (blockIdx.z) { case 0: src = w0; break; case 1: src = w1; break;
                        case 2: src = w2; break; default: src = w3; }
  short* dhi = wt + (size_t)(2 * blockIdx.z) * (1024u * 1024u);
  short* dlo = dhi + (size_t)(1024u * 1024u);
  const int x = threadIdx.x, y = threadIdx.y;            // (32, 8)
  const int c0 = blockIdx.x * 32, r0 = blockIdx.y * 32;
#pragma unroll
  for (int i = 0; i < 4; i++)
    tile[y + 8 * i][x] = src[(size_t)(r0 + y + 8 * i) * 1024 + c0 + x];
  __syncthreads();
#pragma unroll
  for (int i = 0; i < 4; i++) {
    float v = tile[x][y + 8 * i];
    short sh, sl; split1(v, sh, sl);
    const size_t off = (size_t)(c0 + y + 8 * i) * 1024 + r0 + x;
    dhi[off] = sh; dlo[off] = sl;
  }
}

// ---------------------------------------------------------------------------
// Streaming activation prep: fp32 -> bf16 hi/lo (split) or bf16 (cvt).
// ---------------------------------------------------------------------------
__global__ __launch_bounds__(256) void kprep_split(
    const float* __restrict__ src, short* __restrict__ hi, short* __restrict__ lo)
{
  const int n8 = (M_ * D_) / 8;
  for (int i = blockIdx.x * blockDim.x + threadIdx.x; i < n8;
       i += gridDim.x * blockDim.x) {
    f32x4 a = *(const f32x4*)(src + (size_t)i * 8);
    f32x4 b = *(const f32x4*)(src + (size_t)i * 8 + 4);
    bf16x8 h, l;
#pragma unroll
    for (int j = 0; j < 4; j++) {
      short sh, sl;
      split1(a[j], sh, sl); h[j] = sh;     l[j] = sl;
      split1(b[j], sh, sl); h[4 + j] = sh; l[4 + j] = sl;
    }
    *(bf16x8*)(hi + (size_t)i * 8) = h;
    *(bf16x8*)(lo + (size_t)i * 8) = l;
  }
}

__global__ __launch_bounds__(256) void kprep_cvt(
    const float* __restrict__ src, short* __restrict__ dst)
{
  const int n8 = (M_ * D_) / 8;
  for (int i = blockIdx.x * blockDim.x + threadIdx.x; i < n8;
       i += gridDim.x * blockDim.x) {
    f32x4 a = *(const f32x4*)(src + (size_t)i * 8);
    f32x4 b = *(const f32x4*)(src + (size_t)i * 8 + 4);
    bf16x8 h;
#pragma unroll
    for (int j = 0; j < 4; j++) { h[j] = f2bf(a[j]); h[4 + j] = f2bf(b[j]); }
    *(bf16x8*)(dst + (size_t)i * 8) = h;
  }
}

// ---------------------------------------------------------------------------
// Split-precision projection: C = (Ahi+Alo)(Whi+Wlo) dropping lo*lo.
// A pre-split bf16; out = head-split [B,H,S,dk] bf16 hi/lo pairs.
// 128x128 tile, 4 waves, BK=32. One z (Q or K) per launch.
// ---------------------------------------------------------------------------
__global__ __launch_bounds__(256, 4) void kproj(
    const short* __restrict__ ahig, const short* __restrict__ alog,
    const short* __restrict__ whi,  const short* __restrict__ wlo,
    short* __restrict__ ohi, short* __restrict__ olo, float scale)
{
  __shared__ short Ahi[128][40];
  __shared__ short Alo[128][40];
  __shared__ short Whi[128][40];
  __shared__ short Wlo[128][40];

  const int m0 = blockIdx.x * 128;
  const int n0 = blockIdx.y * 128;

  const int tid  = threadIdx.x;
  const int w    = tid >> 6, lane = tid & 63;
  const int g    = lane >> 4, x = lane & 15;
  const int wr   = w >> 1, wc = w & 1;
  const int srow = tid >> 1, shalf = tid & 1;

  f32x4 acc[4][4];
#pragma unroll
  for (int mi = 0; mi < 4; mi++)
#pragma unroll
    for (int ni = 0; ni < 4; ni++) acc[mi][ni] = f32x4{0.f, 0.f, 0.f, 0.f};

  for (int k0 = 0; k0 < 1024; k0 += 32) {
    const size_t aoff = (size_t)(m0 + srow) * 1024 + k0 + shalf * 16;
    const size_t woff = (size_t)(n0 + srow) * 1024 + k0 + shalf * 16;
    *(bf16x8*)&Ahi[srow][shalf * 16 + 0] = *(const bf16x8*)(ahig + aoff);
    *(bf16x8*)&Ahi[srow][shalf * 16 + 8] = *(const bf16x8*)(ahig + aoff + 8);
    *(bf16x8*)&Alo[srow][shalf * 16 + 0] = *(const bf16x8*)(alog + aoff);
    *(bf16x8*)&Alo[srow][shalf * 16 + 8] = *(const bf16x8*)(alog + aoff + 8);
    *(bf16x8*)&Whi[srow][shalf * 16 + 0] = *(const bf16x8*)(whi + woff);
    *(bf16x8*)&Whi[srow][shalf * 16 + 8] = *(const bf16x8*)(whi + woff + 8);
    *(bf16x8*)&Wlo[srow][shalf * 16 + 0] = *(const bf16x8*)(wlo + woff);
    *(bf16x8*)&Wlo[srow][shalf * 16 + 8] = *(const bf16x8*)(wlo + woff + 8);
    __syncthreads();

    bf16x8 ah[4], al[4], bh[4], bl[4];
#pragma unroll
    for (int mi = 0; mi < 4; mi++) {
      ah[mi] = *(const bf16x8*)&Ahi[wr * 64 + mi * 16 + x][8 * g];
      al[mi] = *(const bf16x8*)&Alo[wr * 64 + mi * 16 + x][8 * g];
    }
#pragma unroll
    for (int ni = 0; ni < 4; ni++) {
      bh[ni] = *(const bf16x8*)&Whi[wc * 64 + ni * 16 + x][8 * g];
      bl[ni] = *(const bf16x8*)&Wlo[wc * 64 + ni * 16 + x][8 * g];
    }
    __builtin_amdgcn_s_setprio(1);
#pragma unroll
    for (int mi = 0; mi < 4; mi++)
#pragma unroll
      for (int ni = 0; ni < 4; ni++) {
        acc[mi][ni] = __builtin_amdgcn_mfma_f32_16x16x32_bf16(
            ah[mi], bh[ni], acc[mi][ni], 0, 0, 0);
        acc[mi][ni] = __builtin_amdgcn_mfma_f32_16x16x32_bf16(
            ah[mi], bl[ni], acc[mi][ni], 0, 0, 0);
        acc[mi][ni] = __builtin_amdgcn_mfma_f32_16x16x32_bf16(
            al[mi], bh[ni], acc[mi][ni], 0, 0, 0);
      }
    __builtin_amdgcn_s_setprio(0);
    __syncthreads();
  }

  // ---- epilogue: scale, split, write [B,H,S,dk] hi/lo ----
#pragma unroll
  for (int mi = 0; mi < 4; mi++) {
    const int mrow = m0 + wr * 64 + mi * 16 + g * 4;
#pragma unroll
    for (int ni = 0; ni < 4; ni++) {
      const int ncol = n0 + wc * 64 + ni * 16 + x;
#pragma unroll
      for (int r = 0; r < 4; r++) {
        const float v = acc[mi][ni][r] * scale;
        const int row = mrow + r;
        const int b = row >> 11, s = row & 2047;
        const int hh = ncol >> 6, dd = ncol & 63;
        const size_t off = (((size_t)b * H_ + hh) * S_ + s) * DK_ + dd;
        short sh, sl; split1(v, sh, sl);
        ohi[off] = sh; olo[off] = sl;
      }
    }
  }
}

// ---------------------------------------------------------------------------
// Plain bf16 GEMM, A bf16 flat. MODE 0: out bf16 head layout (V projection).
//                               MODE 1: out fp32 flat (out projection).
// ---------------------------------------------------------------------------
template<int MODE>
__global__ __launch_bounds__(256, 4) void kgemm(
    const short* __restrict__ ab, const short* __restrict__ wtp,
    short* __restrict__ outb, float* __restrict__ outf)
{
  __shared__ short Alds[128][40];
  __shared__ short Wlds[128][40];

  const int m0 = blockIdx.x * 128;
  const int n0 = blockIdx.y * 128;

  const int tid  = threadIdx.x;
  const int w    = tid >> 6, lane = tid & 63;
  const int g    = lane >> 4, x = lane & 15;
  const int wr   = w >> 1, wc = w & 1;
  const int srow = tid >> 1, shalf = tid & 1;

  f32x4 acc[4][4];
#pragma unroll
  for (int mi = 0; mi < 4; mi++)
#pragma unroll
    for (int ni = 0; ni < 4; ni++) acc[mi][ni] = f32x4{0.f, 0.f, 0.f, 0.f};

  for (int k0 = 0; k0 < 1024; k0 += 32) {
    const size_t aoff = (size_t)(m0 + srow) * 1024 + k0 + shalf * 16;
    const size_t woff = (size_t)(n0 + srow) * 1024 + k0 + shalf * 16;
    *(bf16x8*)&Alds[srow][shalf * 16 + 0] = *(const bf16x8*)(ab + aoff);
    *(bf16x8*)&Alds[srow][shalf * 16 + 8] = *(const bf16x8*)(ab + aoff + 8);
    *(bf16x8*)&Wlds[srow][shalf * 16 + 0] = *(const bf16x8*)(wtp + woff);
    *(bf16x8*)&Wlds[srow][shalf * 16 + 8] = *(const bf16x8*)(wtp + woff + 8);
    __syncthreads();

    bf16x8 afr[4], bfr[4];
#pragma unroll
    for (int mi = 0; mi < 4; mi++)
      afr[mi] = *(const bf16x8*)&Alds[wr * 64 + mi * 16 + x][8 * g];
#pragma unroll
    for (int ni = 0; ni < 4; ni++)
      bfr[ni] = *(const bf16x8*)&Wlds[wc * 64 + ni * 16 + x][8 * g];
    __builtin_amdgcn_s_setprio(1);
#pragma unroll
    for (int mi = 0; mi < 4; mi++)
#pragma unroll
      for (int ni = 0; ni < 4; ni++)
        acc[mi][ni] = __builtin_amdgcn_mfma_f32_16x16x32_bf16(
            afr[mi], bfr[ni], acc[mi][ni], 0, 0, 0);
    __builtin_amdgcn_s_setprio(0);
    __syncthreads();
  }

#pragma unroll
  for (int mi = 0; mi < 4; mi++) {
    const int mrow = m0 + wr * 64 + mi * 16 + g * 4;
#pragma unroll
    for (int ni = 0; ni < 4; ni++) {
      const int ncol = n0 + wc * 64 + ni * 16 + x;
#pragma unroll
      for (int r = 0; r < 4; r++) {
        const float v = acc[mi][ni][r];
        const int row = mrow + r;
        if constexpr (MODE == 0) {
          const int b = row >> 11, s = row & 2047;
          const int hh = ncol >> 6, dd = ncol & 63;
          outb[(((size_t)b * H_ + hh) * S_ + s) * DK_ + dd] = f2bf(v);
        } else {
          outf[(size_t)row * 1024 + ncol] = v;
        }
      }
    }
  }
}

// ---------------------------------------------------------------------------
// Causal flash attention v3. Q,K bf16 hi/lo (3-MFMA split QK^T), V bf16.
// - 512 threads = 8 waves x 16 q-rows = 128-q tile; KV tile 64 -> staging
//   cost per unit work is 4x lower than the 4-wave version.
// - Pair (p, 15-p): uniform 36 KV-iterations per block.
// - T14 prefetch: next tile's 3 global b128 loads issued before compute,
//   LDS writes after the post-compute barrier (latency hidden).
// - Vt stride 74 shorts: static-index transpose writes are 4-way (cheap),
//   kills the dynamic va[e] extract VALU; frag reads stay ~2-way.
// Grid (8, 64). Scores in log2-domain (scale folded into Q) -> exp2f.
// ---------------------------------------------------------------------------
__global__ __launch_bounds__(512, 4) void kattn(
    const short* __restrict__ Qhi, const short* __restrict__ Qlo,
    const short* __restrict__ Khi, const short* __restrict__ Klo,
    const short* __restrict__ Vh,  short* __restrict__ AO)
{
  __shared__ short KldsH[64][72];
  __shared__ short KldsL[64][72];
  __shared__ short Vtlds[64][74];
  __shared__ short Plds[8][16][72];

  // XCD-chunked bijective swizzle: 512 blocks, 8 XCDs, chunks of 64.
  const int flat = blockIdx.x + (blockIdx.y << 3);   // grid (8, 64)
  const int logical = (flat & 7) * 64 + (flat >> 3);
  const int p  = logical & 7;         // pair index 0..7
  const int bh = logical >> 3;        // 0..63

  const int tid = threadIdx.x;
  const int w = tid >> 6, lane = tid & 63;
  const int g = lane >> 4, x = lane & 15;

  const size_t bhoff = (size_t)bh * S_ * DK_;
  const short* KgH = Khi + bhoff;
  const short* KgL = Klo + bhoff;
  const short* Vg  = Vh + bhoff;

  const int srow = tid >> 3, sc8 = tid & 7;    // staging coords (64 rows x 8)

#pragma unroll
  for (int half = 0; half < 2; half++) {
    const int qt = half ? (15 - p) : p;        // q-tile index 0..15
    const int qb = qt << 7;

    const int qrow = qb + w * 16 + x;
    bf16x8 qfh[2], qfl[2];
#pragma unroll
    for (int ds = 0; ds < 2; ds++) {
      qfh[ds] = *(const bf16x8*)(Qhi + bhoff + (size_t)qrow * DK_ + ds * 32 + 8 * g);
      qfl[ds] = *(const bf16x8*)(Qlo + bhoff + (size_t)qrow * DK_ + ds * 32 + 8 * g);
    }

    f32x4 ow[4];
#pragma unroll
    for (int dt = 0; dt < 4; dt++) ow[dt] = f32x4{0.f, 0.f, 0.f, 0.f};
    float mrow[4], lsum[4];
#pragma unroll
    for (int r = 0; r < 4; r++) { mrow[r] = -1e30f; lsum[r] = 0.f; }

    const int ntiles = 2 * qt + 2;

    // ---- prologue: stage tile 0 directly ----
    {
      const size_t goff = (size_t)srow * DK_ + sc8 * 8;
      bf16x8 kh = *(const bf16x8*)(KgH + goff);
      bf16x8 kl = *(const bf16x8*)(KgL + goff);
      bf16x8 vv = *(const bf16x8*)(Vg + goff);
      *(bf16x8*)&KldsH[srow][sc8 * 8] = kh;
      *(bf16x8*)&KldsL[srow][sc8 * 8] = kl;
#pragma unroll
      for (int e = 0; e < 8; e++) Vtlds[sc8 * 8 + e][srow] = vv[e];
    }

    for (int it = 0; it < ntiles; it++) {
      const int kvb = it << 6;
      __syncthreads();   // staged tile visible to all

      // ---- prefetch next tile into registers (no wait) ----
      bf16x8 nkh, nkl, nvv;
      const bool more = (it + 1 < ntiles);
      if (more) {
        const size_t goff = (size_t)((it + 1) * 64 + srow) * DK_ + sc8 * 8;
        nkh = *(const bf16x8*)(KgH + goff);
        nkl = *(const bf16x8*)(KgL + goff);
        nvv = *(const bf16x8*)(Vg + goff);
      }

      // ---- split QK^T : S[q 16][kv 64] per wave (24 MFMA) ----
      f32x4 sacc[4];
#pragma unroll
      for (int nt = 0; nt < 4; nt++) sacc[nt] = f32x4{0.f, 0.f, 0.f, 0.f};
      __builtin_amdgcn_s_setprio(1);
#pragma unroll
      for (int nt = 0; nt < 4; nt++)
#pragma unroll
        for (int ds = 0; ds < 2; ds++) {
          bf16x8 kfh = *(const bf16x8*)&KldsH[nt * 16 + x][ds * 32 + 8 * g];
          bf16x8 kfl = *(const bf16x8*)&KldsL[nt * 16 + x][ds * 32 + 8 * g];
          sacc[nt] = __builtin_amdgcn_mfma_f32_16x16x32_bf16(
              qfh[ds], kfh, sacc[nt], 0, 0, 0);
          sacc[nt] = __builtin_amdgcn_mfma_f32_16x16x32_bf16(
              qfh[ds], kfl, sacc[nt], 0, 0, 0);
          sacc[nt] = __builtin_amdgcn_mfma_f32_16x16x32_bf16(
              qfl[ds], kfh, sacc[nt], 0, 0, 0);
        }
      __builtin_amdgcn_s_setprio(0);

      // ---- causal mask (only tiles crossing the diagonal for this wave) ----
      if (kvb + 63 > qb + w * 16) {
#pragma unroll
        for (int nt = 0; nt < 4; nt++) {
          const int kvg = kvb + nt * 16 + x;
#pragma unroll
          for (int r = 0; r < 4; r++) {
            const int qg = qb + w * 16 + g * 4 + r;
            if (kvg > qg) sacc[nt][r] = -1e30f;
          }
        }
      }

      // ---- online softmax (log2-domain scores, native exp2) ----
      float mnew[4], alpha[4];
#pragma unroll
      for (int r = 0; r < 4; r++) {
        float t = fmaxf(fmaxf(sacc[0][r], sacc[1][r]),
                        fmaxf(sacc[2][r], sacc[3][r]));
        t = fmaxf(t, __shfl_xor(t, 1));
        t = fmaxf(t, __shfl_xor(t, 2));
        t = fmaxf(t, __shfl_xor(t, 4));
        t = fmaxf(t, __shfl_xor(t, 8));
        mnew[r]  = fmaxf(mrow[r], t);
        alpha[r] = exp2f(mrow[r] - mnew[r]);
        mrow[r]  = mnew[r];
      }
#pragma unroll
      for (int r = 0; r < 4; r++) {
        float rs = 0.f;
#pragma unroll
        for (int nt = 0; nt < 4; nt++) {
          const float pe = exp2f(sacc[nt][r] - mnew[r]);
          sacc[nt][r] = pe;
          rs += pe;
        }
        rs += __shfl_xor(rs, 1);
        rs += __shfl_xor(rs, 2);
        rs += __shfl_xor(rs, 4);
        rs += __shfl_xor(rs, 8);
        lsum[r] = lsum[r] * alpha[r] + rs;
      }
#pragma unroll
      for (int nt = 0; nt < 4; nt++)
#pragma unroll
        for (int r = 0; r < 4; r++)
          Plds[w][g * 4 + r][nt * 16 + x] = f2bf(sacc[nt][r]);
#pragma unroll
      for (int dt = 0; dt < 4; dt++)
#pragma unroll
        for (int r = 0; r < 4; r++) ow[dt][r] *= alpha[r];

      // P writes are per-wave; fence LDS before reading them back
      asm volatile("s_waitcnt lgkmcnt(0)" ::: "memory");
      __builtin_amdgcn_sched_barrier(0);

      // ---- PV : O[q 16][d 64] (8 MFMA) ----
      bf16x8 pf[2];
      pf[0] = *(const bf16x8*)&Plds[w][x][0 * 32 + 8 * g];
      pf[1] = *(const bf16x8*)&Plds[w][x][1 * 32 + 8 * g];
      __builtin_amdgcn_s_setprio(1);
#pragma unroll
      for (int dt = 0; dt < 4; dt++)
#pragma unroll
        for (int ks = 0; ks < 2; ks++) {
          bf16x8 vf = *(const bf16x8*)&Vtlds[dt * 16 + x][ks * 32 + 8 * g];
          ow[dt] = __builtin_amdgcn_mfma_f32_16x16x32_bf16(
              pf[ks], vf, ow[dt], 0, 0, 0);
        }
      __builtin_amdgcn_s_setprio(0);

      __syncthreads();   // all waves done reading this tile
      if (more) {
        *(bf16x8*)&KldsH[srow][sc8 * 8] = nkh;
        *(bf16x8*)&KldsL[srow][sc8 * 8] = nkl;
#pragma unroll
        for (int e = 0; e < 8; e++) Vtlds[sc8 * 8 + e][srow] = nvv[e];
      }
    }

    // ---- epilogue: normalize, write merged-head AO [B,S,D] bf16 ----
    const int b = bh >> 4, h = bh & 15;
#pragma unroll
    for (int r = 0; r < 4; r++) {
      const float inv = 1.0f / lsum[r];
      const int row = qb + w * 16 + g * 4 + r;
      const size_t base = ((size_t)b * S_ + row) * D_ + h * DK_;
#pragma unroll
      for (int dt = 0; dt < 4; dt++)
        AO[base + dt * 16 + x] = f2bf(ow[dt][r] * inv);
    }
  }
}

// ---------------------------------------------------------------------------
extern "C" void kernel_launch(void* const* d_in, const int* in_sizes, int n_in,
                              void* d_out, int out_size, void* d_ws, size_t ws_size,
                              hipStream_t stream) {
  (void)in_sizes; (void)n_in; (void)out_size; (void)ws_size;
  const float* q  = (const float*)d_in[0];
  const float* k  = (const float*)d_in[1];
  const float* v  = (const float*)d_in[2];
  const float* wq = (const float*)d_in[3];
  const float* wk = (const float*)d_in[4];
  const float* wv = (const float*)d_in[5];
  const float* wo = (const float*)d_in[6];
  float* out = (float*)d_out;

  // Workspace layout (MB):
  //   0..16    WT: 8 x [1024][1024] bf16 (wq_hi,wq_lo,wk_hi,wk_lo,wv_hi,wv_lo,wo_hi,wo_lo)
  //   16..32   QHhi  32..48 QHlo  48..64 KHhi  64..80 KHlo  (head-split bf16)
  //   80..96   VH (head-split bf16)
  //   96..112  AO ([B,S,D] bf16)
  //   112..128 As_hi  128..144 As_lo  (activation prep, reused q->k->v)
  char* ws = (char*)d_ws;
  short* WT    = (short*)ws;
  short* QHhi  = (short*)(ws + (size_t)16  * 1024 * 1024);
  short* QHlo  = (short*)(ws + (size_t)32  * 1024 * 1024);
  short* KHhi  = (short*)(ws + (size_t)48  * 1024 * 1024);
  short* KHlo  = (short*)(ws + (size_t)64  * 1024 * 1024);
  short* VH    = (short*)(ws + (size_t)80  * 1024 * 1024);
  short* AO    = (short*)(ws + (size_t)96  * 1024 * 1024);
  short* As_hi = (short*)(ws + (size_t)112 * 1024 * 1024);
  short* As_lo = (short*)(ws + (size_t)128 * 1024 * 1024);

  const short* WQhi = WT;
  const short* WQlo = WT + (size_t)1 * 1024 * 1024;
  const short* WKhi = WT + (size_t)2 * 1024 * 1024;
  const short* WKlo = WT + (size_t)3 * 1024 * 1024;
  const short* WVhi = WT + (size_t)4 * 1024 * 1024;
  const short* WOhi = WT + (size_t)6 * 1024 * 1024;

  const float qscale = 0.18033688011112042f;   // 0.125 * log2(e)

  kw_split<<<dim3(32, 32, 4), dim3(32, 8, 1), 0, stream>>>(wq, wk, wv, wo, WT);

  kprep_split<<<dim3(2048), dim3(256), 0, stream>>>(q, As_hi, As_lo);
  kproj<<<dim3(64, 8), dim3(256), 0, stream>>>(As_hi, As_lo, WQhi, WQlo,
                                               QHhi, QHlo, qscale);
  kprep_split<<<dim3(2048), dim3(256), 0, stream>>>(k, As_hi, As_lo);
  kproj<<<dim3(64, 8), dim3(256), 0, stream>>>(As_hi, As_lo, WKhi, WKlo,
                                               KHhi, KHlo, 1.0f);
  kprep_cvt<<<dim3(2048), dim3(256), 0, stream>>>(v, As_hi);
  kgemm<0><<<dim3(64, 8), dim3(256), 0, stream>>>(As_hi, WVhi, VH, nullptr);

  kattn<<<dim3(8, 64), dim3(512), 0, stream>>>(QHhi, QHlo, KHhi, KHlo, VH, AO);

  kgemm<1><<<dim3(64, 8), dim3(256), 0, stream>>>(AO, WOhi, nullptr, out);
}